// Round 1
// baseline (145.168 us; speedup 1.0000x reference)
//
#include <hip/hip_runtime.h>
#include <hip/hip_bf16.h>
#include <float.h>

// AFM via MFMA, v2: register-pressure relief + explicit per-tile register
// double-buffering.
//
// Theory for this revision: v1 (RPW=4, __launch_bounds__(256,4)) forced a
// <=128 VGPR cap on a ~36x-unrolled body whose live set is ~140+ VGPRs
// (b16[16]+pw16[16]=32 resident weight regs alone) -> scratch spills inside
// the inner loop; spill reloads (~300-600 cy, serialized into the softmax/
// MFMA dependence chain) explain the ~4-10x gap vs the ~12us issue floor.
// Changes:
//   - __launch_bounds__(256,3): VGPR cap ~168 (no spills), still 12 waves/CU.
//   - RPW 4->2: halves the unrolled body (18 tile bodies), -2 idxr regs,
//     grid 1024->2048 for load balance at occupancy 3.
//   - explicit [2]-buffered tile loads: ds_read_b128 for tile t+1 issued
//     before tile t compute -> LDS latency hidden even at lower TLP.
//   - packed f32x4/f32x2 VALU (v_pk_mul/v_pk_fma) for products + gv; the
//     proj dot is split into two independent pk-fma chains for ILP.
//
// Math identical to v1: per 32-pair tile one v_mfma_f32_32x32x16_bf16
// computes h^T = W^T@inner^T with bias preloaded in the accumulator; cross
// term folded in via g_p = inner_p . fc_w; online softmax (m/ssum/gacc).
// bf16 by truncation (v_perm), error ~1e-5 vs 2.2e-2 threshold.

#define FN 24
#define ED 16
#define AS 32
#define NP 276
#define NT 9            // 32-pair tiles (288 slots)
#define LASTV 20        // valid cols in last tile
#define EPITCH 20       // emb LDS row pitch in words (80 B, b128-aligned)
#define RPW 2           // rows per wave
#define NTHR 256
#define FIELD_SIZE 50000

typedef __attribute__((ext_vector_type(8)))  short bf16x8;
typedef __attribute__((ext_vector_type(16))) float f32x16;
typedef __attribute__((ext_vector_type(4)))  float f32x4v;
typedef __attribute__((ext_vector_type(2)))  float f32x2;

union BFR { int i[4]; bf16x8 v; };

__device__ __forceinline__ short f2bf(float x) {
    union { __hip_bfloat16 h; short s; } u;
    u.h = __float2bfloat16(x);
    return u.s;
}

__device__ __forceinline__ void gather_embed(const float* __restrict__ et,
                                             int idxv, int lane,
                                             float4& a, float4& b) {
    const int f0 = lane >> 2, q0 = lane & 3;
    const int id0 = __shfl(idxv, f0, 64);
    const int id1 = __shfl(idxv, 16 + f0, 64);   // only meaningful for lane<32
    a = ((const float4*)(et + (size_t)id0 * ED))[q0];
    if (lane < 32)
        b = ((const float4*)(et + (size_t)id1 * ED))[q0];
}

__device__ __forceinline__ void write_embed(float* __restrict__ buf, int lane,
                                            const float4& a, const float4& b) {
    const int f0 = lane >> 2, q0 = lane & 3;
    *(float4*)&buf[f0 * EPITCH + q0 * 4] = a;
    if (lane < 32)
        *(float4*)&buf[(16 + f0) * EPITCH + q0 * 4] = b;
}

__global__ __launch_bounds__(NTHR, 3) void afm_kernel(
    const int*   __restrict__ x,
    const float* __restrict__ embed_table,
    const float* __restrict__ linear_table,
    const float* __restrict__ linear_bias,
    const float* __restrict__ attn_W,       // [E, A]
    const float* __restrict__ attn_b,       // [A]
    const float* __restrict__ proj_w,       // [A]
    const float* __restrict__ fc_w,         // [E]
    const float* __restrict__ fc_b,
    float*       __restrict__ out,
    int B)
{
    __shared__ float emb_s[NTHR / 64][2][FN * EPITCH];
    __shared__ int   pko_s[NT * 32];

    const int tid  = threadIdx.x;
    const int wave = tid >> 6;
    const int lane = tid & 63;
    const int half = lane >> 5;
    const int col  = lane & 31;
    const int e0   = half * 8;
    const int w0   = (blockIdx.x * (NTHR / 64) + wave) * RPW;

    // ---- pair table, block-cooperative ----
    for (int s = tid; s < NT * 32; s += NTHR) {
        const int p = (s < NP) ? s : (NP - 1);
        const int q = (NP - 1) - p;
        int m = (int)((sqrtf((float)(8 * q + 1)) + 1.0f) * 0.5f);
        if (m * (m + 1) / 2 <= q) ++m;
        if ((m - 1) * m / 2 > q) --m;
        const int fi = (FN - 1) - m;
        const int fj = fi + 1 + (p - (NP - m * (m + 1) / 2));
        pko_s[s] = ((fi * (EPITCH * 4)) << 16) | (fj * (EPITCH * 4));
    }

    // ---- prologue: issue ALL x loads for this wave's rows ----
    int idxr[RPW];
#pragma unroll
    for (int k = 0; k < RPW; ++k) {
        const int r = w0 + k, rc = (r < B) ? r : (B - 1);
        idxr[k] = (lane < FN) ? (x[rc * FN + lane] + lane * FIELD_SIZE) : 0;
    }

    // ---- per-lane weight constants (once per RPW rows) ----
    bf16x8 aW;                          // A-frag: W^T[a=col][k=e0+i]
#pragma unroll
    for (int i = 0; i < 8; ++i) aW[i] = f2bf(attn_W[(e0 + i) * AS + col]);
    float b16[16];                      // D rows: a=(r&3)+8*(r>>2)+4*half
    f32x2 pw2_[8];                      // proj_w packed for pk-fma
#pragma unroll
    for (int r = 0; r < 16; ++r) {
        const int a = (r & 3) + 8 * (r >> 2) + 4 * half;
        b16[r] = attn_b[a];
        if (r & 1) pw2_[r >> 1].y = proj_w[a];
        else       pw2_[r >> 1].x = proj_w[a];
    }
    f32x4v fcwA, fcwB;
#pragma unroll
    for (int i = 0; i < 4; ++i) {
        fcwA[i] = fc_w[e0 + i];
        fcwB[i] = fc_w[e0 + 4 + i];
    }
    const float cbias = linear_bias[0] + fc_b[0];

    // ---- prologue: row 0 gather + LDS write ----
    float linv = (lane < FN) ? linear_table[idxr[0]] : 0.f;
    {
        float4 ga, gb;
        gather_embed(embed_table, idxr[0], lane, ga, gb);
        write_embed(emb_s[wave][0], lane, ga, gb);
    }

    __syncthreads();                    // pko_s ready
    int pk[NT];
#pragma unroll
    for (int t = 0; t < NT; ++t) pk[t] = pko_s[t * 32 + col];

    // ---- main loop over this wave's rows ----
#pragma unroll
    for (int k = 0; k < RPW; ++k) {
        const int row = w0 + k;
        // prefetch row k+1 (emb gather overlaps row-k compute below)
        float4 na, nb; float linn = 0.f;
        if (k + 1 < RPW) {
            linn = (lane < FN) ? linear_table[idxr[k + 1]] : 0.f;
            gather_embed(embed_table, idxr[k + 1], lane, na, nb);
        }

        const char* embb = (const char*)emb_s[wave][k & 1] + half * 32;

        // explicit 2-deep register buffer for tile operands
        f32x4v xi0[2], xi1[2], xj0[2], xj1[2];
        {
            const int oi = pk[0] >> 16, oj = pk[0] & 0xffff;
            xi0[0] = *(const f32x4v*)(embb + oi);
            xi1[0] = *(const f32x4v*)(embb + oi + 16);
            xj0[0] = *(const f32x4v*)(embb + oj);
            xj1[0] = *(const f32x4v*)(embb + oj + 16);
        }

        float m = -FLT_MAX, ssum = 0.f, gacc = 0.f;
#pragma unroll
        for (int t = 0; t < NT; ++t) {
            const int cur = t & 1, nxt = cur ^ 1;
            if (t + 1 < NT) {           // issue next tile's LDS reads first
                const int oi = pk[t + 1] >> 16, oj = pk[t + 1] & 0xffff;
                xi0[nxt] = *(const f32x4v*)(embb + oi);
                xi1[nxt] = *(const f32x4v*)(embb + oi + 16);
                xj0[nxt] = *(const f32x4v*)(embb + oj);
                xj1[nxt] = *(const f32x4v*)(embb + oj + 16);
            }
            const f32x4v pa = xi0[cur] * xj0[cur];       // 2x v_pk_mul_f32
            const f32x4v pb = xi1[cur] * xj1[cur];
            f32x4v g4 = __builtin_elementwise_fma(pb, fcwB, pa * fcwA);
            const float gv = (g4.x + g4.y) + (g4.z + g4.w);
            BFR u;
            u.i[0] = __builtin_amdgcn_perm(__float_as_int(pa.y), __float_as_int(pa.x), 0x07060302);
            u.i[1] = __builtin_amdgcn_perm(__float_as_int(pa.w), __float_as_int(pa.z), 0x07060302);
            u.i[2] = __builtin_amdgcn_perm(__float_as_int(pb.y), __float_as_int(pb.x), 0x07060302);
            u.i[3] = __builtin_amdgcn_perm(__float_as_int(pb.w), __float_as_int(pb.z), 0x07060302);
            f32x16 c;
#pragma unroll
            for (int r = 0; r < 16; ++r) c[r] = b16[r];
            c = __builtin_amdgcn_mfma_f32_32x32x16_bf16(aW, u.v, c, 0, 0, 0);
            const f32x2 z2 = {0.f, 0.f};
            f32x2 sac0 = z2, sac1 = z2;                  // 2 chains for ILP
#pragma unroll
            for (int r2 = 0; r2 < 4; ++r2) {
                f32x2 h0; h0.x = c[2 * r2]; h0.y = c[2 * r2 + 1];
                h0 = __builtin_elementwise_max(h0, z2);
                sac0 = __builtin_elementwise_fma(h0, pw2_[r2], sac0);
                f32x2 h1; h1.x = c[8 + 2 * r2]; h1.y = c[8 + 2 * r2 + 1];
                h1 = __builtin_elementwise_max(h1, z2);
                sac1 = __builtin_elementwise_fma(h1, pw2_[4 + r2], sac1);
            }
            float s = (sac0.x + sac0.y) + (sac1.x + sac1.y);
            s += __shfl_xor(s, 32, 64);        // combine the two a-halves
            const bool valid = (t < NT - 1) || (col < LASTV);
            s = valid ? s : -FLT_MAX;
            // online softmax update
            const float mn   = fmaxf(m, s);
            const float cold = __expf(m - mn);
            const float e    = __expf(s - mn);
            ssum = fmaf(ssum, cold, e);
            gacc = fmaf(gacc, cold, e * gv);
            m = mn;
        }

        // ---- reductions: max (half), rescale, sums ----
        float M = m;
#pragma unroll
        for (int off = 16; off; off >>= 1) M = fmaxf(M, __shfl_xor(M, off, 64));
        const float rs = __expf(m - M);
        ssum *= rs; gacc *= rs;
#pragma unroll
        for (int off = 16; off; off >>= 1) ssum += __shfl_xor(ssum, off, 64);
#pragma unroll
        for (int off = 32; off; off >>= 1) gacc += __shfl_xor(gacc, off, 64);
        float lin = linv;
#pragma unroll
        for (int off = 32; off; off >>= 1) lin += __shfl_xor(lin, off, 64);

        if (row < B && lane == 0)
            out[row] = lin + cbias + gacc / ssum;

        // stage next row's embeddings into the other buffer
        if (k + 1 < RPW) {
            write_embed(emb_s[wave][(k + 1) & 1], lane, na, nb);
            linv = linn;
        }
    }
}

extern "C" void kernel_launch(void* const* d_in, const int* in_sizes, int n_in,
                              void* d_out, int out_size, void* d_ws, size_t ws_size,
                              hipStream_t stream) {
    const int*   x            = (const int*)  d_in[0];
    const float* embed_table  = (const float*)d_in[1];
    const float* linear_table = (const float*)d_in[2];
    const float* linear_bias  = (const float*)d_in[3];
    const float* attn_W       = (const float*)d_in[4];
    const float* attn_b       = (const float*)d_in[5];
    const float* proj_w       = (const float*)d_in[6];
    // d_in[7] = proj_b (softmax-invariant)
    const float* fc_w         = (const float*)d_in[8];
    const float* fc_b         = (const float*)d_in[9];
    float* out = (float*)d_out;

    const int B = in_sizes[0] / FN;
    const int rows_per_block = (NTHR / 64) * RPW;   // 8
    const int grid = (B + rows_per_block - 1) / rows_per_block;
    afm_kernel<<<grid, NTHR, 0, stream>>>(x, embed_table, linear_table,
                                          linear_bias, attn_W, attn_b, proj_w,
                                          fc_w, fc_b, out, B);
}